// Round 8
// baseline (2169.827 us; speedup 1.0000x reference)
//
#include <hip/hip_runtime.h>
#include <math.h>

typedef float f4 __attribute__((ext_vector_type(4)));
typedef float f2 __attribute__((ext_vector_type(2)));

#define THREADS 64
#define HID 256
#define SMP 8    // samples per block == per wave (1 wave, S=8 blocking)

// ---------------- prep: transpose weights into ws ----------------
// ws layout (floats): [0]=W1T 256x256 (W1T[k][n]=W1[n][k]),
//   [65536]=W2T 256x256, [131072]=WoutT 32x256 (WoutT[j][k]=Wout[k][j])
__global__ void k_prep(const float* __restrict__ W1, const float* __restrict__ W2,
                       const float* __restrict__ Wout, float* __restrict__ ws) {
  float* W1T = ws;
  float* W2T = ws + 65536;
  float* WoutT = ws + 131072;
  int tid = blockIdx.x * 256 + threadIdx.x;
  if (tid < 65536) {
    int k = tid >> 8, n = tid & 255;
    W1T[tid] = W1[n * 256 + k];
    W2T[tid] = W2[n * 256 + k];
    if (tid < 8192) {
      int k2 = tid >> 8, n2 = tid & 255;   // WoutT[32][256]
      WoutT[tid] = Wout[n2 * 32 + k2];
    }
  }
}

// softplus = np fp32 semantics (DO NOT TOUCH — mask-critical):
//   sp = max(z,0) + log1pf(expf(-|z|)), each libm call correctly rounded
//   via double intermediates. Verified bit-faithful in rounds 6-8.
__device__ __forceinline__ float sp_cr(float z) {
  float az = fabsf(z);
  float e  = (float)exp(-(double)az);
  float lp = (float)log1p((double)e);
  return fmaxf(z, 0.0f) + lp;
}

// backward factor: sigmoid(z) = 1 - exp(-softplus(z)) from stored activation.
__device__ __forceinline__ float sig_from_h(float h) {
  return 1.0f - __expf(-h);
}

// ---------------- packed-fp32 MAC primitives (VOP3P) ----------------
// v_pk_* f32 = two independent IEEE fp32 ops (half-rate on gfx950 — no cycle
// gain, but halves issue slots). Identical rounding to scalar.
// op_sel broadcasts one component of the h pair to both halves (no movs).

// d = (h[SEL] * w.lo, h[SEL] * w.hi)
template <int SEL>
__device__ __forceinline__ f2 pk_mul_b(f2 h, f2 w) {
  f2 d;
  if constexpr (SEL == 0)
    asm("v_pk_mul_f32 %0, %1, %2 op_sel:[0,0] op_sel_hi:[0,1]"
        : "=v"(d) : "v"(h), "v"(w));
  else
    asm("v_pk_mul_f32 %0, %1, %2 op_sel:[1,0] op_sel_hi:[1,1]"
        : "=v"(d) : "v"(h), "v"(w));
  return d;
}

__device__ __forceinline__ f2 pk_add(f2 a, f2 b) {
  f2 d;
  asm("v_pk_add_f32 %0, %1, %2" : "=v"(d) : "v"(a), "v"(b));
  return d;
}

// a += (h[SEL] * w.lo, h[SEL] * w.hi)   (fma rounding, bwd path)
template <int SEL>
__device__ __forceinline__ void pk_fma_b(f2& a, f2 h, f2 w) {
  if constexpr (SEL == 0)
    asm("v_pk_fma_f32 %0, %1, %2, %0 op_sel:[0,0,0] op_sel_hi:[0,1,1]"
        : "+v"(a) : "v"(h), "v"(w));
  else
    asm("v_pk_fma_f32 %0, %1, %2, %0 op_sel:[1,0,0] op_sel_hi:[1,1,1]"
        : "+v"(a) : "v"(h), "v"(w));
}

// 4 MACs (one k, one sample, 4 cols) using h component SEL of pair hp.
// FWD: mul-then-add separate rounding (np-exact); BWD: fmaf.
template <bool FWD, int SEL>
__device__ __forceinline__ void mac4(f2 (&a)[2], f2 hp, f4 wq) {
  f2 w01 = __builtin_shufflevector(wq, wq, 0, 1);
  f2 w23 = __builtin_shufflevector(wq, wq, 2, 3);
  if constexpr (FWD) {
    a[0] = pk_add(a[0], pk_mul_b<SEL>(hp, w01));
    a[1] = pk_add(a[1], pk_mul_b<SEL>(hp, w23));
  } else {
    pk_fma_b<SEL>(a[0], hp, w01);
    pk_fma_b<SEL>(a[1], hp, w23);
  }
}

// ---------------- forced async weight pipeline (asm) ----------------
// GLOAD4: issue 4 global_load_dwordx4 (k-rows g*4..g*4+3 of the panel) into
// a named register bank. volatile -> compiler cannot sink/merge them.
// WAIT4: s_waitcnt vmcnt(4) carrying "+v" deps on the bank so consuming MACs
// cannot be scheduled above the wait (rule #18 via dataflow).
#define GLOAD4(r0, r1, r2, r3, ptr)                                      \
  asm volatile("global_load_dwordx4 %0, %4, off\n\t"                     \
               "global_load_dwordx4 %1, %4, off offset:1024\n\t"         \
               "global_load_dwordx4 %2, %4, off offset:2048\n\t"         \
               "global_load_dwordx4 %3, %4, off offset:3072"             \
               : "=v"(r0), "=v"(r1), "=v"(r2), "=v"(r3)                  \
               : "v"(ptr))

#define WAIT4(r0, r1, r2, r3)                                            \
  asm volatile("s_waitcnt vmcnt(4)"                                      \
               : "+v"(r0), "+v"(r1), "+v"(r2), "+v"(r3))

#define WAIT0(r0, r1, r2, r3)                                            \
  asm volatile("s_waitcnt vmcnt(0)"                                      \
               : "+v"(r0), "+v"(r1), "+v"(r2), "+v"(r3))

// MAC one 4-k-row group (k = 4g..4g+3, ascending — np-exact order) for all
// SMP samples, weights from a named register bank. 8 samples x 2 acc halves
// = 16 independent dependency chains (no pk-add latency bubbles).
template <int K, bool FWD>
__device__ __forceinline__ void mac_group(f2 (&acc)[SMP][2],
                                          const float* __restrict__ hin,
                                          int g, const f4& w0, const f4& w1,
                                          const f4& w2, const f4& w3) {
  #pragma unroll
  for (int s = 0; s < SMP; ++s) {
    f4 hq = *(const f4*)&hin[(size_t)s * K + g * 4];
    f2 h01 = __builtin_shufflevector(hq, hq, 0, 1);
    f2 h23 = __builtin_shufflevector(hq, hq, 2, 3);
    mac4<FWD, 0>(acc[s], h01, w0);   // k = 4g+0
    mac4<FWD, 1>(acc[s], h01, w1);   // k = 4g+1
    mac4<FWD, 0>(acc[s], h23, w2);   // k = 4g+2
    mac4<FWD, 1>(acc[s], h23, w3);   // k = 4g+3
  }
}

// ---------------- layer: weights streamed from L2, asm-pipelined ------------
// Two 4-row banks, 8 loads in flight, counted vmcnt(4) waits. Each bank's
// MAC body (~512 cy at S=8) covers L2 latency. h rows via own-wave LDS reads.
// Summation order: ascending k, one accumulator per (s,col) -> bit-identical.
template <int K, bool FWD>
__device__ __forceinline__ void layer_g(const float* __restrict__ Wbase,
                                        const float* __restrict__ hin,
                                        int l, f2 (&acc)[SMP][2]) {
  #pragma unroll
  for (int s = 0; s < SMP; ++s) {
    acc[s][0] = (f2){0.f, 0.f};
    acc[s][1] = (f2){0.f, 0.f};
  }
  const float* wp = Wbase + l * 4;
  constexpr int NG = K / 4;            // 4-row groups (8 or 64)
  f4 a0, a1, a2, a3, b0, b1, b2, b3;
  GLOAD4(a0, a1, a2, a3, wp);
  GLOAD4(b0, b1, b2, b3, wp + 1024);
  #pragma unroll 1
  for (int g = 0; g <= NG - 4; g += 2) {
    WAIT4(a0, a1, a2, a3);
    mac_group<K, FWD>(acc, hin, g, a0, a1, a2, a3);
    GLOAD4(a0, a1, a2, a3, wp + (size_t)(g + 2) * 1024);
    WAIT4(b0, b1, b2, b3);
    mac_group<K, FWD>(acc, hin, g + 1, b0, b1, b2, b3);
    GLOAD4(b0, b1, b2, b3, wp + (size_t)(g + 3) * 1024);
  }
  // epilogue: banks A(NG-2), B(NG-1) in flight
  WAIT4(a0, a1, a2, a3);
  mac_group<K, FWD>(acc, hin, NG - 2, a0, a1, a2, a3);
  WAIT0(b0, b1, b2, b3);
  mac_group<K, FWD>(acc, hin, NG - 1, b0, b1, b2, b3);
}

// softplus(acc + b) -> LDS row (scalar adds, same order/rounding as before)
__device__ __forceinline__ void sp_store(const f2 (&a)[2],
                                         const float* __restrict__ b,
                                         float* __restrict__ dstrow, int l) {
  f4 bv = *(const f4*)&b[l * 4];
  f4 o;
  o[0] = sp_cr(a[0][0] + bv[0]);
  o[1] = sp_cr(a[0][1] + bv[1]);
  o[2] = sp_cr(a[1][0] + bv[2]);
  o[3] = sp_cr(a[1][1] + bv[3]);
  *(f4*)&dstrow[l * 4] = o;
}

// dz = acc * sig(h) -> LDS row in-place
__device__ __forceinline__ void sig_store(const f2 (&a)[2],
                                          float* __restrict__ hrow, int l) {
  f4 h = *(f4*)&hrow[l * 4];
  f4 d;
  d[0] = a[0][0] * sig_from_h(h[0]);
  d[1] = a[0][1] * sig_from_h(h[1]);
  d[2] = a[1][0] * sig_from_h(h[2]);
  d[3] = a[1][1] * sig_from_h(h[3]);
  *(f4*)&hrow[l * 4] = d;
}

// ---------------- fused MLP fwd (np-faithful) + bwd + c = dvdx@G ------------
// R16: 1-wave blocks, S=8 sample blocking. (1) Weight L2 traffic halves vs
// S=4 (each 256KB panel read feeds 8 samples): ~34 -> ~17 GB ~= 500 us, now
// far below the ~1400 us VALU floor -> hideable. (2) ZERO barriers: all MAC
// inputs / mask / dz are own-wave LDS rows; within-wave RAW ordered by
// compiler lgkmcnt. (3) 16 independent acc chains remove pk dep bubbles.
// 26 KB LDS -> 6 blocks/CU. asm GLOAD4/WAIT4 pipeline kept (R7-verified).
// Output bit-identical (absmax 0.0004882812) — regression check.
__global__ __launch_bounds__(THREADS, 2) void k_main(
    const float* __restrict__ x,
    const float* __restrict__ W0, const float* __restrict__ b0,
    const float* __restrict__ W1, const float* __restrict__ b1,
    const float* __restrict__ W2, const float* __restrict__ b2,
    const float* __restrict__ Wout, const float* __restrict__ bout,
    const float* __restrict__ G, const float* __restrict__ ws,
    float* __restrict__ out) {
  __shared__ float xs[SMP][32];       // 1 KB
  __shared__ float ha[SMP][HID];      // 8 KB : h0, then dz0
  __shared__ float hb[SMP][HID];      // 8 KB : h1, then dz1
  __shared__ float hc[SMP][HID];      // 8 KB : h2, then dz2
  __shared__ float zm[SMP][32];       // 1 KB : mask, then dvdx

  const float* W1T = ws;
  const float* W2T = ws + 65536;
  const float* WoutT = ws + 131072;

  const int tid = threadIdx.x;
  const int l = tid;                  // lane 0..63 -> cols l*4..l*4+3
  const int s0 = blockIdx.x * SMP;

  {
    const f4* xsrc = (const f4*)(x + (size_t)s0 * 32);
    ((f4*)xs)[tid] = xsrc[tid];       // 64 lanes x 16B = 8x32 floats
  }

  f2 acc[SMP][2];

  // ---- L0: h0 = softplus(xs @ W0 + b0) -> ha  (K=32) ----
  layer_g<32, true>(W0, &xs[0][0], l, acc);
  #pragma unroll
  for (int s = 0; s < SMP; ++s) sp_store(acc[s], b0, &ha[s][0], l);

  // ---- L1: h1 = softplus(h0 @ W1 + b1) -> hb  (K=256) ----
  layer_g<256, true>(W1, &ha[0][0], l, acc);
  #pragma unroll
  for (int s = 0; s < SMP; ++s) sp_store(acc[s], b1, &hb[s][0], l);

  // ---- L2: h2 = softplus(h1 @ W2 + b2) -> hc ----
  layer_g<256, true>(W2, &hb[0][0], l, acc);
  #pragma unroll
  for (int s = 0; s < SMP; ++s) sp_store(acc[s], b2, &hc[s][0], l);

  // ---- L3: z3 = h2 @ Wout + bout ; mask -> zm (exact np order; WoutT rows,
  // ---- L1-cache-resident). 256 (s,j) pairs -> 4 reps of 64 lanes. ----
  {
#pragma clang fp contract(off)
    #pragma unroll
    for (int rep = 0; rep < 4; ++rep) {
      int idx = tid + rep * THREADS;
      int s = idx >> 5, j = idx & 31;
      const float* wrow = WoutT + (size_t)j * 256;   // WoutT[j][k] = Wout[k][j]
      float acc0 = 0.0f;
      #pragma unroll 4
      for (int k = 0; k < 256; k += 4) {
        f4 hv = *(const f4*)&hc[s][k];
        f4 wv = *(const f4*)&wrow[k];
        #pragma unroll
        for (int kk = 0; kk < 4; ++kk) {
          float p = hv[kk] * wv[kk];
          acc0 = acc0 + p;
        }
      }
      zm[s][j] = (acc0 + bout[j] > 0.0f) ? 1.0f : 0.0f;
    }
  }

  // ---- B2: dz2 = (mask @ WoutT) * sig(h2) -> hc in-place (K=32) ----
  layer_g<32, false>(WoutT, &zm[0][0], l, acc);
  #pragma unroll
  for (int s = 0; s < SMP; ++s) sig_store(acc[s], &hc[s][0], l);

  // ---- B1: dz1 = (dz2 @ W2T) * sig(h1) -> hb in-place ----
  layer_g<256, false>(W2T, &hc[0][0], l, acc);
  #pragma unroll
  for (int s = 0; s < SMP; ++s) sig_store(acc[s], &hb[s][0], l);

  // ---- B0: dz0 = (dz1 @ W1T) * sig(h0) -> ha in-place ----
  layer_g<256, false>(W1T, &hb[0][0], l, acc);
  #pragma unroll
  for (int s = 0; s < SMP; ++s) sig_store(acc[s], &ha[s][0], l);

  // ---- BX: dvdx = dz0 @ W0T -> zm (W0 rows, cache-resident) ----
  {
    #pragma unroll
    for (int rep = 0; rep < 4; ++rep) {
      int idx = tid + rep * THREADS;
      int s = idx >> 5, j = idx & 31;
      const float* wrow = W0 + (size_t)j * 256;      // W0[j][k]
      float acc0 = 0.0f;
      #pragma unroll 4
      for (int k = 0; k < 256; k += 4) {
        f4 hv = *(const f4*)&ha[s][k];
        f4 wv = *(const f4*)&wrow[k];
        #pragma unroll
        for (int kk = 0; kk < 4; ++kk) {
          acc0 = fmaf(hv[kk], wv[kk], acc0);
        }
      }
      zm[s][j] = acc0;
    }
  }

  // ---- C: c = dvdx @ G -> out ----
  {
    int s = tid >> 3, a = tid & 7;    // 64 lanes = 8 samples x 8 actions
    float acc0 = 0.0f;
    #pragma unroll
    for (int j = 0; j < 32; ++j) acc0 = fmaf(zm[s][j], G[j * 8 + a], acc0);
    out[(size_t)(s0 + s) * 8 + a] = acc0;
  }
}

// ---------------- BoxCDQP: in-place on d_out (c -> u) ----------------
__global__ __launch_bounds__(256) void k_qp(float* __restrict__ out,
                                            const float* __restrict__ R,
                                            const float* __restrict__ lower,
                                            const float* __restrict__ upper) {
  int t = blockIdx.x * 256 + threadIdx.x;
  float q[8][8], u[8], cc[8], lo[8], hi[8], dg[8];
  #pragma unroll
  for (int i = 0; i < 8; ++i) {
    lo[i] = lower[i];
    hi[i] = upper[i];
    u[i] = 0.0f;
    cc[i] = out[(size_t)t * 8 + i];
    #pragma unroll
    for (int j = 0; j < 8; ++j) q[i][j] = 2.0f * R[i * 8 + j];
  }
  #pragma unroll
  for (int i = 0; i < 8; ++i) dg[i] = q[i][i];

  #pragma unroll 1
  for (int it = 0; it < 30; ++it) {
    #pragma unroll
    for (int i = 0; i < 8; ++i) {
      float g = cc[i];
      #pragma unroll
      for (int j = 0; j < 8; ++j) g = fmaf(q[i][j], u[j], g);
      float v = u[i] - g / dg[i];
      u[i] = fminf(fmaxf(v, lo[i]), hi[i]);
    }
  }
  #pragma unroll
  for (int i = 0; i < 8; ++i) out[(size_t)t * 8 + i] = u[i];
}

extern "C" void kernel_launch(void* const* d_in, const int* in_sizes, int n_in,
                              void* d_out, int out_size, void* d_ws, size_t ws_size,
                              hipStream_t stream) {
  const float* x    = (const float*)d_in[0];
  // d_in[1] = t (unused)
  const float* W0   = (const float*)d_in[2];
  const float* b0   = (const float*)d_in[3];
  const float* W1   = (const float*)d_in[4];
  const float* b1   = (const float*)d_in[5];
  const float* W2   = (const float*)d_in[6];
  const float* b2   = (const float*)d_in[7];
  const float* Wout = (const float*)d_in[8];
  const float* bout = (const float*)d_in[9];
  const float* G    = (const float*)d_in[10];
  const float* R    = (const float*)d_in[11];
  const float* lower= (const float*)d_in[12];
  const float* upper= (const float*)d_in[13];
  float* out = (float*)d_out;
  float* ws  = (float*)d_ws;

  const int B = in_sizes[0] / 32;   // 131072

  k_prep<<<256, 256, 0, stream>>>(W1, W2, Wout, ws);
  k_main<<<B / SMP, THREADS, 0, stream>>>(x, W0, b0, W1, b1, W2, b2,
                                          Wout, bout, G, ws, out);
  k_qp<<<B / 256, 256, 0, stream>>>(out, R, lower, upper);
}